// Round 7
// baseline (37.215 us; speedup 1.0000x reference)
//
#include <hip/hip_runtime.h>
#include <math.h>

#define HW 4096
#define NCH 4
#define TPB 256                               // 4 waves/block
#define G 32                                  // lanes per group
#define RPG 2                                 // rows register-tiled per group
#define ROWS_PER_BLOCK 16                     // 4 waves x 2 groups x 2 rows
#define BLOCKS_PER_CH (HW / ROWS_PER_BLOCK)   // 256
#define NBLOCKS (NCH * BLOCKS_PER_CH)         // 1024
#define KNN 5

// digamma for positive integer args (here always >= 5).
// Shift-up recurrence to x >= 6, then asymptotic series. ~1e-7 abs error.
__device__ __forceinline__ float digammaf_dev(float x) {
    float r = 0.f;
    while (x < 6.f) { r -= 1.f / x; x += 1.f; }
    float f = 1.f / x, f2 = f * f;
    return logf(x) - 0.5f * f
         - f2 * (1.f / 12.f - f2 * (1.f / 120.f - f2 * (1.f / 252.f))) + r;
}

// Insert d into ascending sorted 6-list (drop the max).
// s0' = min(s0,d); si' = med3(s[i-1], s[i], d) -- 6 independent v_med3_f32.
__device__ __forceinline__ void insert6(float (&s)[6], float d) {
    float n0 = fminf(s[0], d);
    float n1 = __builtin_amdgcn_fmed3f(s[0], s[1], d);
    float n2 = __builtin_amdgcn_fmed3f(s[1], s[2], d);
    float n3 = __builtin_amdgcn_fmed3f(s[2], s[3], d);
    float n4 = __builtin_amdgcn_fmed3f(s[3], s[4], d);
    float n5 = __builtin_amdgcn_fmed3f(s[4], s[5], d);
    s[0] = n0; s[1] = n1; s[2] = n2; s[3] = n3; s[4] = n4; s[5] = n5;
}

__global__ __launch_bounds__(TPB, 4) void knnmi_rows(const float* __restrict__ x,
                                                     const float* __restrict__ y,
                                                     float* __restrict__ ws) {
    __shared__ float2 sxy[HW];                 // 32 KB interleaved {x,y}
    __shared__ float red[8];                   // one partial per (wave,group)

    const int c  = blockIdx.x >> 8;            // channel 0..3
    const int rb = blockIdx.x & 255;           // row-block within channel

    const float* xc = x + c * HW;
    const float* yc = y + c * HW;

    // Stage interleaved {x,y} via float4 loads + b128 LDS writes (4 iters).
    for (int i = threadIdx.x; i < HW / 4; i += TPB) {
        float4 xv = ((const float4*)xc)[i];
        float4 yv = ((const float4*)yc)[i];
        ((float4*)sxy)[2 * i]     = make_float4(xv.x, yv.x, xv.y, yv.y);
        ((float4*)sxy)[2 * i + 1] = make_float4(xv.z, yv.z, xv.w, yv.w);
    }
    __syncthreads();

    const int wv   = threadIdx.x >> 6;         // wave 0..3
    const int lane = threadIdx.x & 63;
    const int l    = lane & (G - 1);           // lane within 32-lane group
    const int g    = lane >> 5;                // group 0..1
    const int r0   = rb * ROWS_PER_BLOCK + wv * 4 + g * RPG;   // first of 2 rows

    // Each group's 2 rows, register-tiled: one candidate read serves both.
    float xr[RPG], yr[RPG];
#pragma unroll
    for (int r = 0; r < RPG; ++r) {
        float2 p = sxy[r0 + r];                // near-uniform addr -> broadcast
        xr[r] = p.x; yr[r] = p.y;
    }

    const float4* f4 = (const float4*)sxy;     // entry f = candidates (2f, 2f+1)

    // Pass 1: lane reads 2 candidates per ds_read_b128 at f = it*32 + l.
    // 64 iters cover all 4096 candidates per group; both groups read the
    // same 32 addresses (broadcast). Each read feeds BOTH rows of the group.
    float s[RPG][6];
#pragma unroll
    for (int r = 0; r < RPG; ++r)
#pragma unroll
        for (int q = 0; q < 6; ++q) s[r][q] = 3.4e38f;

#pragma unroll 4
    for (int it = 0; it < HW / (2 * G); ++it) {      // 64 iters
        float4 p = f4[it * G + l];                   // {x0,y0,x1,y1}
#pragma unroll
        for (int r = 0; r < RPG; ++r) {
            float d0 = fmaxf(fabsf(xr[r] - p.x), fabsf(yr[r] - p.y));
            float d1 = fmaxf(fabsf(xr[r] - p.z), fabsf(yr[r] - p.w));
            insert6(s[r], d0);
            insert6(s[r], d1);
        }
    }

    // Merge 32 per-lane sorted 6-lists within each group (5 butterfly
    // stages, masks 1..16 stay inside the 32-lane group). Both groups and
    // both rows ride the same wave-wide shuffle ops.
#pragma unroll
    for (int m = 1; m < G; m <<= 1) {
#pragma unroll
        for (int r = 0; r < RPG; ++r) {
            float o[6];
#pragma unroll
            for (int q = 0; q < 6; ++q) o[q] = __shfl_xor(s[r][q], m);
#pragma unroll
            for (int q = 0; q < 6; ++q) insert6(s[r], o[q]);
        }
    }

    float eps[RPG];
#pragma unroll
    for (int r = 0; r < RPG; ++r) eps[r] = s[r][5]; // (k+1)-th smallest

    // Pass 2: strict-< marginal counts (self included, as in ref).
    int nx[RPG] = {0, 0}, ny[RPG] = {0, 0};
#pragma unroll 4
    for (int it = 0; it < HW / (2 * G); ++it) {
        float4 p = f4[it * G + l];
#pragma unroll
        for (int r = 0; r < RPG; ++r) {
            nx[r] += (fabsf(xr[r] - p.x) < eps[r]);
            ny[r] += (fabsf(yr[r] - p.y) < eps[r]);
            nx[r] += (fabsf(xr[r] - p.z) < eps[r]);
            ny[r] += (fabsf(yr[r] - p.w) < eps[r]);
        }
    }

    // Cross-lane count reduce within group (per-lane <= 128, totals <= 4096).
    int pk[RPG];
#pragma unroll
    for (int r = 0; r < RPG; ++r) pk[r] = (nx[r] << 16) | ny[r];
#pragma unroll
    for (int m = 1; m < G; m <<= 1)
#pragma unroll
        for (int r = 0; r < RPG; ++r) pk[r] += __shfl_xor(pk[r], m);

    if (l == 0) {
        float v = 0.f;
#pragma unroll
        for (int r = 0; r < RPG; ++r)
            v += digammaf_dev((float)(pk[r] >> 16))
               + digammaf_dev((float)(pk[r] & 0xffff));
        red[wv * 2 + g] = v;                   // per-(wave,group) partial
    }
    __syncthreads();

    if (threadIdx.x == 0) {
        float v = 0.f;
#pragma unroll
        for (int q = 0; q < 8; ++q) v += red[q];
        ws[blockIdx.x] = v;                    // 1 partial per block
    }
}

__global__ void knnmi_final(const float* __restrict__ ws, float* __restrict__ out) {
    const int w    = threadIdx.x >> 6;    // wave = channel
    const int lane = threadIdx.x & 63;
    float sum = 0.f;
#pragma unroll
    for (int i = lane; i < BLOCKS_PER_CH; i += 64) sum += ws[w * BLOCKS_PER_CH + i];
#pragma unroll
    for (int m = 32; m; m >>= 1) sum += __shfl_xor(sum, m);
    if (lane == 0) {
        float mi = digammaf_dev((float)KNN) + digammaf_dev((float)HW)
                 - sum / (float)HW;
        out[w] = fmaxf(mi, 0.f);
    }
}

extern "C" void kernel_launch(void* const* d_in, const int* in_sizes, int n_in,
                              void* d_out, int out_size, void* d_ws, size_t ws_size,
                              hipStream_t stream) {
    const float* x = (const float*)d_in[0];
    const float* y = (const float*)d_in[1];
    float* out = (float*)d_out;
    float* ws  = (float*)d_ws;   // NBLOCKS floats, fully rewritten every call

    knnmi_rows<<<NBLOCKS, TPB, 0, stream>>>(x, y, ws);
    knnmi_final<<<1, NCH * 64, 0, stream>>>(ws, out);
}